// Round 3
// baseline (598.154 us; speedup 1.0000x reference)
//
#include <hip/hip_runtime.h>
#include <hip/hip_bf16.h>
#include <cstdint>
#include <cstddef>

typedef __hip_bfloat16 bf16;
typedef _Float16 f16;
typedef __attribute__((ext_vector_type(4))) float f32x4;
typedef __attribute__((ext_vector_type(8))) _Float16 f16x8;
typedef __attribute__((ext_vector_type(4))) _Float16 f16x4;
typedef __attribute__((ext_vector_type(4))) unsigned short u16x4;

#define BB 8
#define NN 1024
#define KK 16
#define DD 256
#define MM (BB * NN)   // 8192 rows
#define NLAYER 3
#define NBLK 512       // 2 blocks/CU on 256 CUs -- co-resident for grid barrier
#define NTHR 256

__device__ __forceinline__ float ldf(const void* p, size_t i, int isf32) {
  return isf32 ? ((const float*)p)[i] : __bfloat162float(((const bf16*)p)[i]);
}

__device__ __forceinline__ f32x4 ldf4(const void* p, size_t vi, int isf32) {
  f32x4 r;
  if (isf32) {
    r = ((const f32x4*)p)[vi];
  } else {
    u16x4 u = ((const u16x4*)p)[vi];
#pragma unroll
    for (int q = 0; q < 4; q++) {
      union { unsigned u; float f; } c;
      c.u = ((unsigned)u[q]) << 16;
      r[q] = c.f;
    }
  }
  return r;
}

__device__ __forceinline__ void gload_lds16(const void* g, void* l) {
  __builtin_amdgcn_global_load_lds(
      (const __attribute__((address_space(1))) unsigned int*)g,
      (__attribute__((address_space(3))) unsigned int*)l, 16, 0, 0);
}

// per-WAVE dtype detect: lane i samples W_in u16[2i]; ballot-vote. No barriers.
__device__ __forceinline__ int detect_isf32_wave(const void* W) {
  int lane = threadIdx.x & 63;
  unsigned short b = ((const unsigned short*)W)[2 * lane];
  int e = (b >> 7) & 0xFF;
  int sane = ((e >= 105 && e <= 130) || (b & 0x7FFF) == 0) ? 1 : 0;
  unsigned long long m = __ballot(sane);
  return (__popcll(m) > 32) ? 0 : 1;
}

// fast transcendentals: v_exp_f32 + v_rcp_f32; clamp keeps them NaN-free.
__device__ __forceinline__ float fsigmoid(float x) {
  float a = fminf(fmaxf(-1.44269504f * x, -126.f), 126.f);
  float e = __builtin_amdgcn_exp2f(a);
  return __builtin_amdgcn_rcpf(1.f + e);
}
__device__ __forceinline__ float ftanh(float x) {
  float a = fminf(fmaxf(2.88539008f * x, -126.f), 126.f);
  float e = __builtin_amdgcn_exp2f(a);
  return 1.f - 2.f * __builtin_amdgcn_rcpf(1.f + e);
}

struct Params {
  const void *h0, *c0, *x_in, *x_out, *W_in, *U_in, *W_out, *U_out, *bvec;
  const void *in_mask, *out_mask, *node_mask;
  const int *in_nodes, *out_nodes;
  float *biasI, *nmF, *inmF, *outmF, *XW;
  f16 *h_cur, *c_cur, *A_buf, *X_buf, *BT_W, *BT_U;
  unsigned* bar;   // bar[0]=generation, bar[1]=arrive count (zeroed each launch)
  void* outp;
};

// ---------------- device-scope grid barrier (generation counter) ----------------
// Same mechanism cg::grid_group::sync uses: fence(release) -> atomic arrive ->
// last resets count then bumps generation; others spin on coherent-point RMW
// loads (atomicAdd(p,0) -- plain/volatile loads can hit stale per-XCD L2).
__device__ __forceinline__ void grid_sync(unsigned* bar) {
  __syncthreads();
  if (threadIdx.x == 0) {
    __threadfence();                               // release: drain our writes
    unsigned gen = atomicAdd(&bar[0], 0u);         // read gen BEFORE arriving
    if (atomicAdd(&bar[1], 1u) == (unsigned)gridDim.x - 1u) {
      atomicExch(&bar[1], 0u);                     // reset count (coherent point)
      atomicAdd(&bar[0], 1u);                      // release waiters
    } else {
      while (atomicAdd(&bar[0], 0u) == gen) __builtin_amdgcn_s_sleep(2);
    }
    __threadfence();                               // acquire: inv stale L1/L2
  }
  __syncthreads();
}

// ---------------- phase: prep (transpose + convert/pack) ----------------
// blocks 0..255 transpose one 64x64 tile of one weight matrix into BT_W/BT_U
//   rows n = 4e+g, cols: BT_W=[W_in|W_out], BT_U=[U_in|U_out], stride 512
// then ALL blocks grid-stride the vectorized converts (one vec4 per item).
#define PREP_VEC_TOTAL (256 + 2048 + 32768 + 32768 + 524288 + 524288)
__device__ void prep_phase(const Params& p, char* smem, int isf32) {
  int b = blockIdx.x;
  int t = threadIdx.x;

  if (b < 256) {   // ---- transpose path (16.6 KB of the 32 KB smem) ----
    float (*tile)[65] = (float(*)[65])smem;
    int bx = b & 3, by = (b >> 2) & 3, z = b >> 4;
    int g = z & 3, which = z >> 2;
    const void* src = (which == 0) ? p.W_in : (which == 1) ? p.W_out
                     : (which == 2) ? p.U_in : p.U_out;
    f16* dst = (which < 2) ? p.BT_W : p.BT_U;
    int colofs = (which & 1) * 256;
    size_t gbase = (size_t)g * DD * DD;
    int tx = t & 63, ty = t >> 6;
    int d0 = bx * 64, e0 = by * 64;
#pragma unroll
    for (int r = 0; r < 64; r += 4)
      tile[ty + r][tx] = ldf(src, gbase + (size_t)(d0 + ty + r) * DD + e0 + tx, isf32);
    __syncthreads();
#pragma unroll
    for (int r = 0; r < 64; r += 4)
      dst[(size_t)(4 * (e0 + ty + r) + g) * 512 + colofs + d0 + tx] = (f16)tile[tx][ty + r];
  }

  // ---- vectorized prep: grid-stride, one vec4 per item ----
  const size_t V0 = 256;           // bias vec4s
  const size_t V1 = V0 + 2048;     // node_mask
  const size_t V2 = V1 + 32768;    // in_mask
  const size_t V3 = V2 + 32768;    // out_mask
  const size_t V4 = V3 + 524288;   // h0 + c0
  const size_t V5 = V4 + 524288;   // x pack
  for (size_t i = (size_t)b * NTHR + t; i < V5; i += (size_t)NBLK * NTHR) {
    if (i < V0) {
      f32x4 r;
#pragma unroll
      for (int g = 0; g < 4; g++) r[g] = ldf(p.bvec, (size_t)g * 256 + i, isf32);
      ((f32x4*)p.biasI)[i] = r;
    } else if (i < V1) {
      ((f32x4*)p.nmF)[i - V0] = ldf4(p.node_mask, i - V0, isf32);
    } else if (i < V2) {
      ((f32x4*)p.inmF)[i - V1] = ldf4(p.in_mask, i - V1, isf32);
    } else if (i < V3) {
      ((f32x4*)p.outmF)[i - V2] = ldf4(p.out_mask, i - V2, isf32);
    } else if (i < V4) {
      size_t j = i - V3;
      f32x4 hv = ldf4(p.h0, j, isf32);
      f32x4 cv = ldf4(p.c0, j, isf32);
      f16x4 ho, co;
#pragma unroll
      for (int q = 0; q < 4; q++) { ho[q] = (f16)hv[q]; co[q] = (f16)cv[q]; }
      ((f16x4*)p.h_cur)[j] = ho;
      ((f16x4*)p.c_cur)[j] = co;
    } else {
      size_t j = i - V4;
      size_t m = j >> 6, d4 = (j & 63) * 4;
      f32x4 xi = ldf4(p.x_in, j, isf32);
      f32x4 xo = ldf4(p.x_out, j, isf32);
      f16x4 a, bq;
#pragma unroll
      for (int q = 0; q < 4; q++) { a[q] = (f16)xi[q]; bq[q] = (f16)xo[q]; }
      *(f16x4*)(p.X_buf + m * 512 + d4)       = a;
      *(f16x4*)(p.X_buf + m * 512 + 256 + d4) = bq;
    }
  }
}

// ---------------- phase: gather (one wave per node, 4 nodes per wave) ----------------
__device__ void gather_phase(const Params& p) {
  int gid = blockIdx.x, t = threadIdx.x;
  int wave = t >> 6, lane = t & 63;
  int l5 = lane & 31, dir = lane >> 5;
#pragma unroll
  for (int it = 0; it < 4; it++) {
    int m = gid * 16 + it * 4 + wave;
    int myidx = 0; float mymask = 0.f;
    if (lane < 16)      { myidx = p.in_nodes[(size_t)m * KK + lane];
                          mymask = p.inmF[(size_t)m * KK + lane]; }
    else if (lane < 32) { myidx = p.out_nodes[(size_t)m * KK + lane - 16];
                          mymask = p.outmF[(size_t)m * KK + lane - 16]; }
    const f16* hb = p.h_cur + (size_t)(m >> 10) * NN * DD;
    float acc[8] = {};
#pragma unroll
    for (int k = 0; k < KK; k++) {
      int src = dir * 16 + k;
      int idxk = __shfl(myidx, src);
      float wk = __shfl(mymask, src);
      f16x8 v = *(const f16x8*)(hb + (size_t)idxk * DD + l5 * 8);
#pragma unroll
      for (int q = 0; q < 8; q++) acc[q] += wk * (float)v[q];
    }
    float nm = p.nmF[m];
    f16x8 o;
#pragma unroll
    for (int q = 0; q < 8; q++) o[q] = (f16)(acc[q] * nm);
    *(f16x8*)(p.A_buf + (size_t)m * 512 + dir * 256 + l5 * 8) = o;
  }
}

// ---------------- fp16 MFMA GEMM core: K=512, BM=128 BN=128 BK=64 ----------------
// 4 waves as 2x2; each wave owns a 64x64 quadrant = acc[4][4]. Chunk-swizzled LDS
// (pre-swizzled global src, linear global_load_lds dest, swizzled ds_read).
__device__ __forceinline__ void gemm_core(const f16* gA, const f16* gB, char* smem,
                                          int t, int mBase, int nBase,
                                          f32x4 (&acc)[4][4]) {
  f16* As = (f16*)smem;                  // [128][64] f16 (16 KB)
  f16* Bs = (f16*)(smem + 16384);        // [128][64] f16 (16 KB)
  int w = t >> 6, lane = t & 63;
  int wr = w >> 1, wc = w & 1;
  int row16 = lane & 15, kgrp = lane >> 4;
  int aoff[2][4], boff[2][4];
#pragma unroll
  for (int sub = 0; sub < 2; sub++) {
    int ch = ((sub * 4 + kgrp) ^ (row16 & 7)) * 8;
#pragma unroll
    for (int i = 0; i < 4; i++) aoff[sub][i] = (wr * 64 + 16 * i + row16) * 64 + ch;
#pragma unroll
    for (int j = 0; j < 4; j++) boff[sub][j] = (wc * 64 + 16 * j + row16) * 64 + ch;
  }
  int srow = t >> 3;                       // 0..31
  int scol = ((t & 7) ^ (srow & 7)) * 8;   // pre-swizzled source chunk
  const f16* ga0 = gA + (size_t)(mBase + srow) * 512 + scol;
  const f16* gb0 = gB + (size_t)(nBase + srow) * 512 + scol;
  for (int kt = 0; kt < 512; kt += 64) {
#pragma unroll
    for (int q = 0; q < 4; q++)
      gload_lds16(ga0 + kt + (size_t)(32 * q) * 512, As + q * 2048 + t * 8);
#pragma unroll
    for (int q = 0; q < 4; q++)
      gload_lds16(gb0 + kt + (size_t)(32 * q) * 512, Bs + q * 2048 + t * 8);
    __syncthreads();
#pragma unroll
    for (int sub = 0; sub < 2; sub++) {
      f16x8 af[4], bfr[4];
#pragma unroll
      for (int i = 0; i < 4; i++) af[i] = *(const f16x8*)(As + aoff[sub][i]);
#pragma unroll
      for (int j = 0; j < 4; j++) bfr[j] = *(const f16x8*)(Bs + boff[sub][j]);
#pragma unroll
      for (int i = 0; i < 4; i++)
#pragma unroll
        for (int j = 0; j < 4; j++)
          acc[i][j] = __builtin_amdgcn_mfma_f32_16x16x32_f16(af[i], bfr[j], acc[i][j], 0, 0, 0);
    }
    __syncthreads();
  }
}

// ---------------- phase: gemmx = [x_in|x_out] @ [W_in|W_out]^T + b -> XW (raw frags) ----
__device__ void gemmx_phase(const Params& p, char* smem) {
  int gid = blockIdx.x, t = threadIdx.x;
  int w = t >> 6, lane = t & 63;
  int wc = w & 1, row16 = lane & 15;
  int mb = gid & 63, nb = gid >> 6;
  f32x4 acc[4][4] = {};
  gemm_core(p.X_buf, p.BT_W, smem, t, mb * 128, nb * 128, acc);
  float bb4[4];
#pragma unroll
  for (int j = 0; j < 4; j++) bb4[j] = p.biasI[nb * 128 + wc * 64 + 16 * j + row16];
  f32x4* dst = (f32x4*)p.XW + ((size_t)(nb * 64 + mb) * 256 + t) * 16;
#pragma unroll
  for (int i = 0; i < 4; i++)
#pragma unroll
    for (int j = 0; j < 4; j++) {
      f32x4 v = acc[i][j];
#pragma unroll
      for (int r = 0; r < 4; r++) v[r] += bb4[j];
      dst[i * 4 + j] = v;
    }
}

// ---------------- phase: layer GEMM = [h_in|h_out] @ [U_in|U_out]^T + LSTM epilogue ----
__device__ void gemm_phase(const Params& p, char* smem, int last, int isf32) {
  float* tileF = (float*)smem;           // [128][64] f32 epilogue tile (32 KB)
  int gid = blockIdx.x, t = threadIdx.x;
  int w = t >> 6, lane = t & 63;
  int wr = w >> 1, wc = w & 1;
  int row16 = lane & 15, kgrp = lane >> 4;
  int mb = gid & 63, nb = gid >> 6;
  int mBase = mb * 128, nBase = nb * 128;
  f32x4 acc[4][4];
  const f32x4* xw = (const f32x4*)p.XW + ((size_t)(nb * 64 + mb) * 256 + t) * 16;
#pragma unroll
  for (int i = 0; i < 4; i++)
#pragma unroll
    for (int j = 0; j < 4; j++) acc[i][j] = xw[i * 4 + j];
  gemm_core(p.A_buf, p.BT_U, smem, t, mBase, nBase, acc);

#pragma unroll
  for (int pp = 0; pp < 2; pp++) {
    __syncthreads();
    if (wc == pp) {
#pragma unroll
      for (int i = 0; i < 4; i++)
#pragma unroll
        for (int j = 0; j < 4; j++) {
          int cl = 16 * j + row16;
#pragma unroll
          for (int r = 0; r < 4; r++) {
            int rr = wr * 64 + 16 * i + 4 * kgrp + r;
            int ch = (cl >> 2) ^ (rr & 7);
            tileF[rr * 64 + ch * 4 + (cl & 3)] = acc[i][j][r];
          }
        }
    }
    __syncthreads();
    int el = t & 15;
    int nb2 = nBase + 64 * pp;
    int eb = nb2 >> 2;
#pragma unroll
    for (int rep = 0; rep < 8; rep++) {
      int ml = rep * 16 + (t >> 4);
      int gm = mBase + ml;
      f32x4 vals = *(const f32x4*)(tileF + ml * 64 + ((el ^ (ml & 7))) * 4);
      float nm = p.nmF[gm];
      size_t ci = (size_t)gm * DD + eb + el;
      float cold = (float)p.c_cur[ci];
      float ig = fsigmoid(vals[0]);
      float og = fsigmoid(vals[1]);
      float fg = fsigmoid(vals[2]);
      float gg = ftanh(vals[3]);
      float cn = (fg * cold + ig * gg) * nm;
      float hn = og * ftanh(cn) * nm;
      p.c_cur[ci] = (f16)cn;
      p.h_cur[ci] = (f16)hn;
      if (last) {
        if (isf32) ((float*)p.outp)[ci] = hn;
        else       ((bf16*)p.outp)[ci] = __float2bfloat16(hn);
      }
    }
  }
}

// ---------------- the single persistent kernel ----------------
// 512 blocks x 256 thr, 2 blocks/CU guaranteed (VGPR<=256 via launch_bounds,
// LDS 32 KB). 7 grid barriers replace 7 kernel launches.
__global__ __launch_bounds__(NTHR, 2)
void fused_k(Params p) {
  __shared__ __attribute__((aligned(16))) char smem[32768];
  int isf32 = detect_isf32_wave(p.W_in);

  prep_phase(p, smem, isf32);
  grid_sync(p.bar);
  gather_phase(p);             // layer 0 gather (h_cur from prep)
  gemmx_phase(p, smem);        // layer-invariant x-part (independent of gather)
  grid_sync(p.bar);
  gemm_phase(p, smem, 0, isf32);
  grid_sync(p.bar);
  gather_phase(p);             // layer 1
  grid_sync(p.bar);
  gemm_phase(p, smem, 0, isf32);
  grid_sync(p.bar);
  gather_phase(p);             // layer 2
  grid_sync(p.bar);
  gemm_phase(p, smem, 1, isf32);
}

// ==================== launch ====================
extern "C" void kernel_launch(void* const* d_in, const int* in_sizes, int n_in,
                              void* d_out, int out_size, void* d_ws, size_t ws_size,
                              hipStream_t stream) {
  char* ws = (char*)d_ws;
  f16*   h_cur = (f16*)(ws + 256);                      // 4 MB (first 256 B = barrier)
  f16*   c_cur = h_cur + (size_t)MM * DD;               // 4 MB
  f16*   A_buf = c_cur + (size_t)MM * DD;               // 8 MB  [h_in|h_out], stride 512
  f16*   X_buf = A_buf + (size_t)MM * 512;              // 8 MB  [x_in|x_out], stride 512
  f16*   BT_W  = X_buf + (size_t)MM * 512;              // 1 MB  rows 4e+g, cols [W_in|W_out]
  f16*   BT_U  = BT_W + (size_t)1024 * 512;             // 1 MB  rows 4e+g, cols [U_in|U_out]
  float* XW    = (float*)(BT_U + (size_t)1024 * 512);   // 32 MB raw acc fragments
  float* biasI = XW + (size_t)MM * 1024;                // 4 KB
  float* nmF   = biasI + 1024;
  float* inmF  = nmF + MM;
  float* outmF = inmF + (size_t)MM * KK;

  Params p;
  p.h0 = d_in[0]; p.c0 = d_in[1]; p.x_in = d_in[2]; p.x_out = d_in[3];
  p.W_in = d_in[4]; p.U_in = d_in[5]; p.W_out = d_in[6]; p.U_out = d_in[7];
  p.bvec = d_in[8]; p.in_mask = d_in[9]; p.out_mask = d_in[10]; p.node_mask = d_in[11];
  p.in_nodes = (const int*)d_in[12]; p.out_nodes = (const int*)d_in[13];
  p.biasI = biasI; p.nmF = nmF; p.inmF = inmF; p.outmF = outmF; p.XW = XW;
  p.h_cur = h_cur; p.c_cur = c_cur; p.A_buf = A_buf; p.X_buf = X_buf;
  p.BT_W = BT_W; p.BT_U = BT_U;
  p.bar = (unsigned*)ws;
  p.outp = d_out;
  // d_in[14] = num_layers (3 from setup; hardcoded for graph capture)

  // workspace is poison-filled each iteration: re-zero the barrier words in-stream
  hipMemsetAsync(ws, 0, 8, stream);
  void* kargs[] = {(void*)&p};
  if (hipLaunchCooperativeKernel((void*)fused_k, dim3(NBLK), dim3(NTHR),
                                 kargs, 0, stream) != hipSuccess) {
    // co-residency still holds by occupancy arithmetic (2 blocks/CU, 512 <= 1024 slots)
    fused_k<<<NBLK, NTHR, 0, stream>>>(p);
  }
}

// Round 4
// 218.414 us; speedup vs baseline: 2.7386x; 2.7386x over previous
//
#include <hip/hip_runtime.h>
#include <hip/hip_bf16.h>
#include <cstdint>
#include <cstddef>

typedef __hip_bfloat16 bf16;
typedef _Float16 f16;
typedef __attribute__((ext_vector_type(4))) float f32x4;
typedef __attribute__((ext_vector_type(8))) _Float16 f16x8;
typedef __attribute__((ext_vector_type(4))) _Float16 f16x4;
typedef __attribute__((ext_vector_type(4))) unsigned short u16x4;

#define BB 8
#define NN 1024
#define KK 16
#define DD 256
#define MM (BB * NN)   // 8192 rows
#define NLAYER 3

__device__ __forceinline__ float ldf(const void* p, size_t i, int isf32) {
  return isf32 ? ((const float*)p)[i] : __bfloat162float(((const bf16*)p)[i]);
}

__device__ __forceinline__ f32x4 ldf4(const void* p, size_t vi, int isf32) {
  f32x4 r;
  if (isf32) {
    r = ((const f32x4*)p)[vi];
  } else {
    u16x4 u = ((const u16x4*)p)[vi];
#pragma unroll
    for (int q = 0; q < 4; q++) {
      union { unsigned u; float f; } c;
      c.u = ((unsigned)u[q]) << 16;
      r[q] = c.f;
    }
  }
  return r;
}

__device__ __forceinline__ void gload_lds16(const void* g, void* l) {
  __builtin_amdgcn_global_load_lds(
      (const __attribute__((address_space(1))) unsigned int*)g,
      (__attribute__((address_space(3))) unsigned int*)l, 16, 0, 0);
}

// per-WAVE dtype detect: lane i samples W_in u16[2i]; ballot-vote. No barriers.
__device__ __forceinline__ int detect_isf32_wave(const void* W) {
  int lane = threadIdx.x & 63;
  unsigned short b = ((const unsigned short*)W)[2 * lane];
  int e = (b >> 7) & 0xFF;
  int sane = ((e >= 105 && e <= 130) || (b & 0x7FFF) == 0) ? 1 : 0;
  unsigned long long m = __ballot(sane);
  return (__popcll(m) > 32) ? 0 : 1;
}

// fast transcendentals: v_exp_f32 + v_rcp_f32; clamp keeps them NaN-free.
__device__ __forceinline__ float fsigmoid(float x) {
  float a = fminf(fmaxf(-1.44269504f * x, -126.f), 126.f);
  float e = __builtin_amdgcn_exp2f(a);
  return __builtin_amdgcn_rcpf(1.f + e);
}
__device__ __forceinline__ float ftanh(float x) {
  float a = fminf(fmaxf(2.88539008f * x, -126.f), 126.f);
  float e = __builtin_amdgcn_exp2f(a);
  return 1.f - 2.f * __builtin_amdgcn_rcpf(1.f + e);
}

struct Params {
  const void *h0, *c0, *x_in, *x_out, *W_in, *U_in, *W_out, *U_out, *bvec;
  const void *in_mask, *out_mask, *node_mask;
  const int *in_nodes, *out_nodes;
  float *biasI, *nmF, *inmF, *outmF;
  f16 *h_cur, *c_cur, *A_buf, *X_buf, *BT_W, *BT_U, *XW;
  void* outp;
};

// ---------------- merged prep + weight transpose ----------------
// blocks 0..255: transpose one 64x64 tile of one weight matrix into BT_W/BT_U
//   rows n = 4e+g, cols: BT_W=[W_in|W_out], BT_U=[U_in|U_out], stride 512
// blocks 256+: vectorized converts / packing (4 elems per thread)
#define PREP_VEC_TOTAL (256 + 2048 + 32768 + 32768 + 524288 + 524288)
#define PREP_BLOCKS (256 + (PREP_VEC_TOTAL + 255) / 256)
__global__ void prep_k(Params p) {
  __shared__ float tile[64][65];
  int isf32 = detect_isf32_wave(p.W_in);
  int b = blockIdx.x;
  int t = threadIdx.x;

  if (b < 256) {   // ---- transpose path ----
    int bx = b & 3, by = (b >> 2) & 3, z = b >> 4;
    int g = z & 3, which = z >> 2;
    const void* src = (which == 0) ? p.W_in : (which == 1) ? p.W_out
                     : (which == 2) ? p.U_in : p.U_out;
    f16* dst = (which < 2) ? p.BT_W : p.BT_U;
    int colofs = (which & 1) * 256;
    size_t gbase = (size_t)g * DD * DD;
    int tx = t & 63, ty = t >> 6;
    int d0 = bx * 64, e0 = by * 64;
#pragma unroll
    for (int r = 0; r < 64; r += 4)
      tile[ty + r][tx] = ldf(src, gbase + (size_t)(d0 + ty + r) * DD + e0 + tx, isf32);
    __syncthreads();
#pragma unroll
    for (int r = 0; r < 64; r += 4)
      dst[(size_t)(4 * (e0 + ty + r) + g) * 512 + colofs + d0 + tx] = (f16)tile[tx][ty + r];
    return;
  }

  // ---- vectorized prep path: one vec4 per thread ----
  size_t i = (size_t)(b - 256) * 256 + t;
  const size_t V0 = 256;           // bias vec4s
  const size_t V1 = V0 + 2048;     // node_mask
  const size_t V2 = V1 + 32768;    // in_mask
  const size_t V3 = V2 + 32768;    // out_mask
  const size_t V4 = V3 + 524288;   // h0 + c0
  const size_t V5 = V4 + 524288;   // x pack
  if (i < V0) {
    f32x4 r;
#pragma unroll
    for (int g = 0; g < 4; g++) r[g] = ldf(p.bvec, (size_t)g * 256 + i, isf32);
    ((f32x4*)p.biasI)[i] = r;
  } else if (i < V1) {
    ((f32x4*)p.nmF)[i - V0] = ldf4(p.node_mask, i - V0, isf32);
  } else if (i < V2) {
    ((f32x4*)p.inmF)[i - V1] = ldf4(p.in_mask, i - V1, isf32);
  } else if (i < V3) {
    ((f32x4*)p.outmF)[i - V2] = ldf4(p.out_mask, i - V2, isf32);
  } else if (i < V4) {
    size_t j = i - V3;
    f32x4 hv = ldf4(p.h0, j, isf32);
    f32x4 cv = ldf4(p.c0, j, isf32);
    f16x4 ho, co;
#pragma unroll
    for (int q = 0; q < 4; q++) { ho[q] = (f16)hv[q]; co[q] = (f16)cv[q]; }
    ((f16x4*)p.h_cur)[j] = ho;
    ((f16x4*)p.c_cur)[j] = co;
  } else if (i < V5) {
    size_t j = i - V4;
    size_t m = j >> 6, d4 = (j & 63) * 4;
    f32x4 xi = ldf4(p.x_in, j, isf32);
    f32x4 xo = ldf4(p.x_out, j, isf32);
    f16x4 a, bq;
#pragma unroll
    for (int q = 0; q < 4; q++) { a[q] = (f16)xi[q]; bq[q] = (f16)xo[q]; }
    *(f16x4*)(p.X_buf + m * 512 + d4)       = a;
    *(f16x4*)(p.X_buf + m * 512 + 256 + d4) = bq;
  }
}

// ---------------- gather: one wave per node, shfl broadcast, f16x8 loads ----------------
__global__ void gather_k(Params p) {
  int wave = threadIdx.x >> 6;
  int lane = threadIdx.x & 63;
  int m = blockIdx.x * 4 + wave;
  int l5 = lane & 31, dir = lane >> 5;
  int myidx = 0; float mymask = 0.f;
  if (lane < 16)      { myidx = p.in_nodes[(size_t)m * KK + lane];
                        mymask = p.inmF[(size_t)m * KK + lane]; }
  else if (lane < 32) { myidx = p.out_nodes[(size_t)m * KK + lane - 16];
                        mymask = p.outmF[(size_t)m * KK + lane - 16]; }
  const f16* hb = p.h_cur + (size_t)(m >> 10) * NN * DD;
  float acc[8] = {};
#pragma unroll
  for (int k = 0; k < KK; k++) {
    int src = dir * 16 + k;
    int idxk = __shfl(myidx, src);
    float wk = __shfl(mymask, src);
    f16x8 v = *(const f16x8*)(hb + (size_t)idxk * DD + l5 * 8);
#pragma unroll
    for (int q = 0; q < 8; q++) acc[q] += wk * (float)v[q];
  }
  float nm = p.nmF[m];
  f16x8 o;
#pragma unroll
  for (int q = 0; q < 8; q++) o[q] = (f16)(acc[q] * nm);
  *(f16x8*)(p.A_buf + (size_t)m * 512 + dir * 256 + l5 * 8) = o;
}

// ---------------- fp16 MFMA GEMM core: K=512, BM=128 BN=128 BK=64, DOUBLE-BUFFERED ----
// 4 waves as 2x2; each wave owns a 64x64 quadrant = acc[4][4]. LDS = 2 x 32 KB
// buffers (A 16 KB + B 16 KB each); free occupancy-wise: grid=512 -> only 2
// blocks/CU ever resident, 2 x 64 KB = 128 <= 160 KB.
// Schedule per K-step (T3-minimal): issue next-tile global_load_lds BEFORE the
// ds_read+MFMA of the current tile; the barrier's vmcnt(0) drain then lands after
// MFMA has covered the load latency -> per-step cost max(stage, compute), not sum.
__device__ __forceinline__ void gemm_core(const f16* gA, const f16* gB, char* smem,
                                          int t, int mBase, int nBase,
                                          f32x4 (&acc)[4][4]) {
  int w = t >> 6, lane = t & 63;
  int wr = w >> 1, wc = w & 1;
  int row16 = lane & 15, kgrp = lane >> 4;
  int aoff[2][4], boff[2][4];
#pragma unroll
  for (int sub = 0; sub < 2; sub++) {
    int ch = ((sub * 4 + kgrp) ^ (row16 & 7)) * 8;
#pragma unroll
    for (int i = 0; i < 4; i++) aoff[sub][i] = (wr * 64 + 16 * i + row16) * 64 + ch;
#pragma unroll
    for (int j = 0; j < 4; j++) boff[sub][j] = (wc * 64 + 16 * j + row16) * 64 + ch;
  }
  int srow = t >> 3;                       // 0..31
  int scol = ((t & 7) ^ (srow & 7)) * 8;   // pre-swizzled source chunk
  const f16* ga0 = gA + (size_t)(mBase + srow) * 512 + scol;
  const f16* gb0 = gB + (size_t)(nBase + srow) * 512 + scol;

  // prologue: stage K-tile 0 into buffer 0
  {
    f16* As = (f16*)smem;
    f16* Bs = (f16*)(smem + 16384);
#pragma unroll
    for (int q = 0; q < 4; q++)
      gload_lds16(ga0 + (size_t)(32 * q) * 512, As + q * 2048 + t * 8);
#pragma unroll
    for (int q = 0; q < 4; q++)
      gload_lds16(gb0 + (size_t)(32 * q) * 512, Bs + q * 2048 + t * 8);
  }
  __syncthreads();   // compiler emits vmcnt(0) drain here

#pragma unroll
  for (int it = 0; it < 8; it++) {
    int cur = it & 1;
    if (it < 7) {    // issue NEXT tile's loads before computing current
      int kt = (it + 1) * 64;
      f16* As = (f16*)(smem + (cur ^ 1) * 32768);
      f16* Bs = (f16*)(smem + (cur ^ 1) * 32768 + 16384);
#pragma unroll
      for (int q = 0; q < 4; q++)
        gload_lds16(ga0 + kt + (size_t)(32 * q) * 512, As + q * 2048 + t * 8);
#pragma unroll
      for (int q = 0; q < 4; q++)
        gload_lds16(gb0 + kt + (size_t)(32 * q) * 512, Bs + q * 2048 + t * 8);
    }
    f16* As = (f16*)(smem + cur * 32768);
    f16* Bs = (f16*)(smem + cur * 32768 + 16384);
#pragma unroll
    for (int sub = 0; sub < 2; sub++) {
      f16x8 af[4], bfr[4];
#pragma unroll
      for (int i = 0; i < 4; i++) af[i] = *(const f16x8*)(As + aoff[sub][i]);
#pragma unroll
      for (int j = 0; j < 4; j++) bfr[j] = *(const f16x8*)(Bs + boff[sub][j]);
#pragma unroll
      for (int i = 0; i < 4; i++)
#pragma unroll
        for (int j = 0; j < 4; j++)
          acc[i][j] = __builtin_amdgcn_mfma_f32_16x16x32_f16(af[i], bfr[j], acc[i][j], 0, 0, 0);
    }
    __syncthreads();  // waits next-tile loads (covered by MFMA above) + LDS reuse
  }
}

// ---------------- layer-invariant precompute: XW = [x_in|x_out] @ [W_in|W_out]^T + b ----
// Stores acc fragments as f16 raw frags (reg layout) -> 16 MB, halved traffic.
__global__ __launch_bounds__(256, 2)
void gemmx_k(Params p) {
  __shared__ __attribute__((aligned(16))) char smem[65536];
  int t = threadIdx.x;
  int w = t >> 6, lane = t & 63;
  int wc = w & 1, row16 = lane & 15;
  int mBase = blockIdx.x * 128, nBase = blockIdx.y * 128;
  f32x4 acc[4][4] = {};
  gemm_core(p.X_buf, p.BT_W, smem, t, mBase, nBase, acc);
  // bias per acc column: n = nBase + wc*64 + 16*j + row16 (independent of i, r)
  float bb4[4];
#pragma unroll
  for (int j = 0; j < 4; j++) bb4[j] = p.biasI[nBase + wc * 64 + 16 * j + row16];
  f16x4* dst = (f16x4*)p.XW + ((size_t)(blockIdx.y * 64 + blockIdx.x) * 256 + t) * 16;
#pragma unroll
  for (int i = 0; i < 4; i++)
#pragma unroll
    for (int j = 0; j < 4; j++) {
      f16x4 v;
#pragma unroll
      for (int r = 0; r < 4; r++) v[r] = (f16)(acc[i][j][r] + bb4[j]);
      dst[i * 4 + j] = v;
    }
}

// ---------------- per-layer GEMM: [h_in|h_out] @ [U_in|U_out]^T, acc init = XW ----------
__global__ __launch_bounds__(256, 2)
void gemm_k(Params p, int last) {
  __shared__ __attribute__((aligned(16))) char smem[65536];
  float* tileF = (float*)smem;           // [128][64] f32 epilogue tile (32 KB)
  int isf32 = detect_isf32_wave(p.W_in);
  int t = threadIdx.x;
  int w = t >> 6, lane = t & 63;
  int wr = w >> 1, wc = w & 1;
  int row16 = lane & 15, kgrp = lane >> 4;
  int mBase = blockIdx.x * 128, nBase = blockIdx.y * 128;
  f32x4 acc[4][4];
  const f16x4* xw = (const f16x4*)p.XW + ((size_t)(blockIdx.y * 64 + blockIdx.x) * 256 + t) * 16;
#pragma unroll
  for (int i = 0; i < 4; i++)
#pragma unroll
    for (int j = 0; j < 4; j++) {
      f16x4 v = xw[i * 4 + j];
#pragma unroll
      for (int r = 0; r < 4; r++) acc[i][j][r] = (float)v[r];
    }
  gemm_core(p.A_buf, p.BT_U, smem, t, mBase, nBase, acc);

#pragma unroll
  for (int pp = 0; pp < 2; pp++) {
    __syncthreads();
    if (wc == pp) {
#pragma unroll
      for (int i = 0; i < 4; i++)
#pragma unroll
        for (int j = 0; j < 4; j++) {
          int cl = 16 * j + row16;
#pragma unroll
          for (int r = 0; r < 4; r++) {
            int rr = wr * 64 + 16 * i + 4 * kgrp + r;
            int ch = (cl >> 2) ^ (rr & 7);
            tileF[rr * 64 + ch * 4 + (cl & 3)] = acc[i][j][r];
          }
        }
    }
    __syncthreads();
    int el = t & 15;
    int nb2 = nBase + 64 * pp;
    int eb = nb2 >> 2;
#pragma unroll
    for (int rep = 0; rep < 8; rep++) {
      int ml = rep * 16 + (t >> 4);
      int gm = mBase + ml;
      f32x4 vals = *(const f32x4*)(tileF + ml * 64 + ((el ^ (ml & 7))) * 4);
      float nm = p.nmF[gm];
      size_t ci = (size_t)gm * DD + eb + el;
      float cold = (float)p.c_cur[ci];
      float ig = fsigmoid(vals[0]);
      float og = fsigmoid(vals[1]);
      float fg = fsigmoid(vals[2]);
      float gg = ftanh(vals[3]);
      float cn = (fg * cold + ig * gg) * nm;
      float hn = og * ftanh(cn) * nm;
      p.c_cur[ci] = (f16)cn;
      p.h_cur[ci] = (f16)hn;
      if (last) {
        if (isf32) ((float*)p.outp)[ci] = hn;
        else       ((bf16*)p.outp)[ci] = __float2bfloat16(hn);
      }
    }
  }
}

// ==================== launch ====================
extern "C" void kernel_launch(void* const* d_in, const int* in_sizes, int n_in,
                              void* d_out, int out_size, void* d_ws, size_t ws_size,
                              hipStream_t stream) {
  char* ws = (char*)d_ws;
  f16*   h_cur = (f16*)(ws + 256);                      // 4 MB
  f16*   c_cur = h_cur + (size_t)MM * DD;               // 4 MB
  f16*   A_buf = c_cur + (size_t)MM * DD;               // 8 MB  [h_in|h_out], stride 512
  f16*   X_buf = A_buf + (size_t)MM * 512;              // 8 MB  [x_in|x_out], stride 512
  f16*   BT_W  = X_buf + (size_t)MM * 512;              // 1 MB  rows 4e+g, cols [W_in|W_out]
  f16*   BT_U  = BT_W + (size_t)1024 * 512;             // 1 MB  rows 4e+g, cols [U_in|U_out]
  f16*   XW    = BT_U + (size_t)1024 * 512;             // 16 MB f16 raw acc fragments
  float* biasI = (float*)(XW + (size_t)MM * 1024);      // 4 KB
  float* nmF   = biasI + 1024;
  float* inmF  = nmF + MM;
  float* outmF = inmF + (size_t)MM * KK;

  Params p;
  p.h0 = d_in[0]; p.c0 = d_in[1]; p.x_in = d_in[2]; p.x_out = d_in[3];
  p.W_in = d_in[4]; p.U_in = d_in[5]; p.W_out = d_in[6]; p.U_out = d_in[7];
  p.bvec = d_in[8]; p.in_mask = d_in[9]; p.out_mask = d_in[10]; p.node_mask = d_in[11];
  p.in_nodes = (const int*)d_in[12]; p.out_nodes = (const int*)d_in[13];
  p.biasI = biasI; p.nmF = nmF; p.inmF = inmF; p.outmF = outmF;
  p.h_cur = h_cur; p.c_cur = c_cur; p.A_buf = A_buf; p.X_buf = X_buf;
  p.BT_W = BT_W; p.BT_U = BT_U; p.XW = XW;
  p.outp = d_out;
  // d_in[14] = num_layers (3 from setup; hardcoded for graph capture)

  prep_k<<<PREP_BLOCKS, 256, 0, stream>>>(p);
  gemmx_k<<<dim3(MM / 128, 8), 256, 0, stream>>>(p);   // once: layer-invariant x-part
  for (int l = 0; l < NLAYER; l++) {
    gather_k<<<MM / 4, 256, 0, stream>>>(p);
    gemm_k<<<dim3(MM / 128, 8), 256, 0, stream>>>(p, l == NLAYER - 1);
  }
}

// Round 5
// 213.103 us; speedup vs baseline: 2.8069x; 1.0249x over previous
//
#include <hip/hip_runtime.h>
#include <hip/hip_bf16.h>
#include <cstdint>
#include <cstddef>

typedef __hip_bfloat16 bf16;
typedef _Float16 f16;
typedef __attribute__((ext_vector_type(4))) float f32x4;
typedef __attribute__((ext_vector_type(8))) _Float16 f16x8;
typedef __attribute__((ext_vector_type(4))) _Float16 f16x4;
typedef __attribute__((ext_vector_type(4))) unsigned short u16x4;

#define BB 8
#define NN 1024
#define KK 16
#define DD 256
#define MM (BB * NN)   // 8192 rows
#define NLAYER 3

__device__ __forceinline__ float ldf(const void* p, size_t i, int isf32) {
  return isf32 ? ((const float*)p)[i] : __bfloat162float(((const bf16*)p)[i]);
}

__device__ __forceinline__ f32x4 ldf4(const void* p, size_t vi, int isf32) {
  f32x4 r;
  if (isf32) {
    r = ((const f32x4*)p)[vi];
  } else {
    u16x4 u = ((const u16x4*)p)[vi];
#pragma unroll
    for (int q = 0; q < 4; q++) {
      union { unsigned u; float f; } c;
      c.u = ((unsigned)u[q]) << 16;
      r[q] = c.f;
    }
  }
  return r;
}

__device__ __forceinline__ void gload_lds16(const void* g, void* l) {
  __builtin_amdgcn_global_load_lds(
      (const __attribute__((address_space(1))) unsigned int*)g,
      (__attribute__((address_space(3))) unsigned int*)l, 16, 0, 0);
}

// per-WAVE dtype detect: lane i samples W_in u16[2i]; ballot-vote. No barriers.
__device__ __forceinline__ int detect_isf32_wave(const void* W) {
  int lane = threadIdx.x & 63;
  unsigned short b = ((const unsigned short*)W)[2 * lane];
  int e = (b >> 7) & 0xFF;
  int sane = ((e >= 105 && e <= 130) || (b & 0x7FFF) == 0) ? 1 : 0;
  unsigned long long m = __ballot(sane);
  return (__popcll(m) > 32) ? 0 : 1;
}

// fast transcendentals: v_exp_f32 + v_rcp_f32; clamp keeps them NaN-free.
__device__ __forceinline__ float fsigmoid(float x) {
  float a = fminf(fmaxf(-1.44269504f * x, -126.f), 126.f);
  float e = __builtin_amdgcn_exp2f(a);
  return __builtin_amdgcn_rcpf(1.f + e);
}
__device__ __forceinline__ float ftanh(float x) {
  float a = fminf(fmaxf(2.88539008f * x, -126.f), 126.f);
  float e = __builtin_amdgcn_exp2f(a);
  return 1.f - 2.f * __builtin_amdgcn_rcpf(1.f + e);
}

struct Params {
  const void *h0, *c0, *x_in, *x_out, *W_in, *U_in, *W_out, *U_out, *bvec;
  const void *in_mask, *out_mask, *node_mask;
  const int *in_nodes, *out_nodes;
  float *biasI, *nmF, *inmF, *outmF;
  f16 *h_cur, *c_cur, *A_buf, *X_buf, *BT_W, *BT_U, *XW;
  void* outp;
};

// ---------------- merged prep + weight transpose ----------------
// blocks 0..255: transpose one 64x64 tile of one weight matrix into BT_W/BT_U
//   rows n = 4e+g, cols: BT_W=[W_in|W_out], BT_U=[U_in|U_out], stride 512
// blocks 256+: vectorized converts / packing (4 elems per thread)
#define PREP_VEC_TOTAL (256 + 2048 + 32768 + 32768 + 524288 + 524288)
#define PREP_BLOCKS (256 + (PREP_VEC_TOTAL + 255) / 256)
__global__ void prep_k(Params p) {
  __shared__ float tile[64][65];
  int isf32 = detect_isf32_wave(p.W_in);
  int b = blockIdx.x;
  int t = threadIdx.x;

  if (b < 256) {   // ---- transpose path ----
    int bx = b & 3, by = (b >> 2) & 3, z = b >> 4;
    int g = z & 3, which = z >> 2;
    const void* src = (which == 0) ? p.W_in : (which == 1) ? p.W_out
                     : (which == 2) ? p.U_in : p.U_out;
    f16* dst = (which < 2) ? p.BT_W : p.BT_U;
    int colofs = (which & 1) * 256;
    size_t gbase = (size_t)g * DD * DD;
    int tx = t & 63, ty = t >> 6;
    int d0 = bx * 64, e0 = by * 64;
#pragma unroll
    for (int r = 0; r < 64; r += 4)
      tile[ty + r][tx] = ldf(src, gbase + (size_t)(d0 + ty + r) * DD + e0 + tx, isf32);
    __syncthreads();
#pragma unroll
    for (int r = 0; r < 64; r += 4)
      dst[(size_t)(4 * (e0 + ty + r) + g) * 512 + colofs + d0 + tx] = (f16)tile[tx][ty + r];
    return;
  }

  // ---- vectorized prep path: one vec4 per thread ----
  size_t i = (size_t)(b - 256) * 256 + t;
  const size_t V0 = 256;           // bias vec4s
  const size_t V1 = V0 + 2048;     // node_mask
  const size_t V2 = V1 + 32768;    // in_mask
  const size_t V3 = V2 + 32768;    // out_mask
  const size_t V4 = V3 + 524288;   // h0 + c0
  const size_t V5 = V4 + 524288;   // x pack
  if (i < V0) {
    f32x4 r;
#pragma unroll
    for (int g = 0; g < 4; g++) r[g] = ldf(p.bvec, (size_t)g * 256 + i, isf32);
    ((f32x4*)p.biasI)[i] = r;
  } else if (i < V1) {
    ((f32x4*)p.nmF)[i - V0] = ldf4(p.node_mask, i - V0, isf32);
  } else if (i < V2) {
    ((f32x4*)p.inmF)[i - V1] = ldf4(p.in_mask, i - V1, isf32);
  } else if (i < V3) {
    ((f32x4*)p.outmF)[i - V2] = ldf4(p.out_mask, i - V2, isf32);
  } else if (i < V4) {
    size_t j = i - V3;
    f32x4 hv = ldf4(p.h0, j, isf32);
    f32x4 cv = ldf4(p.c0, j, isf32);
    f16x4 ho, co;
#pragma unroll
    for (int q = 0; q < 4; q++) { ho[q] = (f16)hv[q]; co[q] = (f16)cv[q]; }
    ((f16x4*)p.h_cur)[j] = ho;
    ((f16x4*)p.c_cur)[j] = co;
  } else if (i < V5) {
    size_t j = i - V4;
    size_t m = j >> 6, d4 = (j & 63) * 4;
    f32x4 xi = ldf4(p.x_in, j, isf32);
    f32x4 xo = ldf4(p.x_out, j, isf32);
    f16x4 a, bq;
#pragma unroll
    for (int q = 0; q < 4; q++) { a[q] = (f16)xi[q]; bq[q] = (f16)xo[q]; }
    *(f16x4*)(p.X_buf + m * 512 + d4)       = a;
    *(f16x4*)(p.X_buf + m * 512 + 256 + d4) = bq;
  }
}

// ---------------- gather: one wave per node, shfl broadcast, f16x8 loads ----------------
// XCD-LOCAL mapping: XCD = blockIdx%8 (round-robin dispatch) handles ONLY batch
// (blockIdx&7). Its h-slice (1024 rows x 512 B = 512 KB) is L2-resident across the
// 16x random reuse, instead of all XCDs thrashing the full 8 MB h_cur through L3.
__global__ void gather_k(Params p) {
  int wave = threadIdx.x >> 6;
  int lane = threadIdx.x & 63;
  int m = (blockIdx.x & 7) * 1024 + (blockIdx.x >> 3) * 4 + wave;
  int l5 = lane & 31, dir = lane >> 5;
  int myidx = 0; float mymask = 0.f;
  if (lane < 16)      { myidx = p.in_nodes[(size_t)m * KK + lane];
                        mymask = p.inmF[(size_t)m * KK + lane]; }
  else if (lane < 32) { myidx = p.out_nodes[(size_t)m * KK + lane - 16];
                        mymask = p.outmF[(size_t)m * KK + lane - 16]; }
  const f16* hb = p.h_cur + (size_t)(m >> 10) * NN * DD;
  float acc[8] = {};
#pragma unroll
  for (int k = 0; k < KK; k++) {
    int src = dir * 16 + k;
    int idxk = __shfl(myidx, src);
    float wk = __shfl(mymask, src);
    f16x8 v = *(const f16x8*)(hb + (size_t)idxk * DD + l5 * 8);
#pragma unroll
    for (int q = 0; q < 8; q++) acc[q] += wk * (float)v[q];
  }
  float nm = p.nmF[m];
  f16x8 o;
#pragma unroll
  for (int q = 0; q < 8; q++) o[q] = (f16)(acc[q] * nm);
  *(f16x8*)(p.A_buf + (size_t)m * 512 + dir * 256 + l5 * 8) = o;
}

// XCD-local m-tile remap for the GEMMs: linear dispatch id = x + 64*y -> XCD = x&7.
// Choose m-tile mt = (x&7)*8 + (x>>3) so the tile's batch (mt>>3) == x&7 == XCD.
// Then: A-panel (written by gather on XCD=batch) is a local-L2 read; the epilogue's
// h/c writes land on the batch's XCD for the NEXT gather; and each XW chunk (keyed
// by raw (y,x), identical in gemmx/gemm) is produced and consumed on one XCD.
__device__ __forceinline__ int mtile_of(int bx) { return (bx & 7) * 8 + (bx >> 3); }

// ---------------- fp16 MFMA GEMM core: K=512, BM=128 BN=128 BK=64, DOUBLE-BUFFERED ----
// 4 waves as 2x2; each wave owns a 64x64 quadrant = acc[4][4]. LDS = 2 x 32 KB
// buffers; free occupancy-wise (grid=512 -> 2 blocks/CU, 2 x 64 KB <= 160 KB).
// Per K-step: issue next-tile global_load_lds BEFORE current ds_read+MFMA.
__device__ __forceinline__ void gemm_core(const f16* gA, const f16* gB, char* smem,
                                          int t, int mBase, int nBase,
                                          f32x4 (&acc)[4][4]) {
  int w = t >> 6, lane = t & 63;
  int wr = w >> 1, wc = w & 1;
  int row16 = lane & 15, kgrp = lane >> 4;
  int aoff[2][4], boff[2][4];
#pragma unroll
  for (int sub = 0; sub < 2; sub++) {
    int ch = ((sub * 4 + kgrp) ^ (row16 & 7)) * 8;
#pragma unroll
    for (int i = 0; i < 4; i++) aoff[sub][i] = (wr * 64 + 16 * i + row16) * 64 + ch;
#pragma unroll
    for (int j = 0; j < 4; j++) boff[sub][j] = (wc * 64 + 16 * j + row16) * 64 + ch;
  }
  int srow = t >> 3;                       // 0..31
  int scol = ((t & 7) ^ (srow & 7)) * 8;   // pre-swizzled source chunk
  const f16* ga0 = gA + (size_t)(mBase + srow) * 512 + scol;
  const f16* gb0 = gB + (size_t)(nBase + srow) * 512 + scol;

  // prologue: stage K-tile 0 into buffer 0
  {
    f16* As = (f16*)smem;
    f16* Bs = (f16*)(smem + 16384);
#pragma unroll
    for (int q = 0; q < 4; q++)
      gload_lds16(ga0 + (size_t)(32 * q) * 512, As + q * 2048 + t * 8);
#pragma unroll
    for (int q = 0; q < 4; q++)
      gload_lds16(gb0 + (size_t)(32 * q) * 512, Bs + q * 2048 + t * 8);
  }
  __syncthreads();   // compiler emits vmcnt(0) drain here

#pragma unroll
  for (int it = 0; it < 8; it++) {
    int cur = it & 1;
    if (it < 7) {    // issue NEXT tile's loads before computing current
      int kt = (it + 1) * 64;
      f16* As = (f16*)(smem + (cur ^ 1) * 32768);
      f16* Bs = (f16*)(smem + (cur ^ 1) * 32768 + 16384);
#pragma unroll
      for (int q = 0; q < 4; q++)
        gload_lds16(ga0 + kt + (size_t)(32 * q) * 512, As + q * 2048 + t * 8);
#pragma unroll
      for (int q = 0; q < 4; q++)
        gload_lds16(gb0 + kt + (size_t)(32 * q) * 512, Bs + q * 2048 + t * 8);
    }
    f16* As = (f16*)(smem + cur * 32768);
    f16* Bs = (f16*)(smem + cur * 32768 + 16384);
#pragma unroll
    for (int sub = 0; sub < 2; sub++) {
      f16x8 af[4], bfr[4];
#pragma unroll
      for (int i = 0; i < 4; i++) af[i] = *(const f16x8*)(As + aoff[sub][i]);
#pragma unroll
      for (int j = 0; j < 4; j++) bfr[j] = *(const f16x8*)(Bs + boff[sub][j]);
#pragma unroll
      for (int i = 0; i < 4; i++)
#pragma unroll
        for (int j = 0; j < 4; j++)
          acc[i][j] = __builtin_amdgcn_mfma_f32_16x16x32_f16(af[i], bfr[j], acc[i][j], 0, 0, 0);
    }
    __syncthreads();  // waits next-tile loads (covered by MFMA above) + LDS reuse
  }
}

// ---------------- layer-invariant precompute: XW = [x_in|x_out] @ [W_in|W_out]^T + b ----
// Stores acc fragments as f16 raw frags (reg layout) -> 16 MB, halved traffic.
__global__ __launch_bounds__(256, 2)
void gemmx_k(Params p) {
  __shared__ __attribute__((aligned(16))) char smem[65536];
  int t = threadIdx.x;
  int w = t >> 6, lane = t & 63;
  int wc = w & 1, row16 = lane & 15;
  int mBase = mtile_of(blockIdx.x) * 128, nBase = blockIdx.y * 128;
  f32x4 acc[4][4] = {};
  gemm_core(p.X_buf, p.BT_W, smem, t, mBase, nBase, acc);
  // bias per acc column: n = nBase + wc*64 + 16*j + row16 (independent of i, r)
  float bb4[4];
#pragma unroll
  for (int j = 0; j < 4; j++) bb4[j] = p.biasI[nBase + wc * 64 + 16 * j + row16];
  f16x4* dst = (f16x4*)p.XW + ((size_t)(blockIdx.y * 64 + blockIdx.x) * 256 + t) * 16;
#pragma unroll
  for (int i = 0; i < 4; i++)
#pragma unroll
    for (int j = 0; j < 4; j++) {
      f16x4 v;
#pragma unroll
      for (int r = 0; r < 4; r++) v[r] = (f16)(acc[i][j][r] + bb4[j]);
      dst[i * 4 + j] = v;
    }
}

// ---------------- per-layer GEMM: [h_in|h_out] @ [U_in|U_out]^T, acc init = XW ----------
__global__ __launch_bounds__(256, 2)
void gemm_k(Params p, int last) {
  __shared__ __attribute__((aligned(16))) char smem[65536];
  float* tileF = (float*)smem;           // [128][64] f32 epilogue tile (32 KB)
  int isf32 = detect_isf32_wave(p.W_in);
  int t = threadIdx.x;
  int w = t >> 6, lane = t & 63;
  int wr = w >> 1, wc = w & 1;
  int row16 = lane & 15, kgrp = lane >> 4;
  int mBase = mtile_of(blockIdx.x) * 128, nBase = blockIdx.y * 128;
  f32x4 acc[4][4];
  const f16x4* xw = (const f16x4*)p.XW + ((size_t)(blockIdx.y * 64 + blockIdx.x) * 256 + t) * 16;
#pragma unroll
  for (int i = 0; i < 4; i++)
#pragma unroll
    for (int j = 0; j < 4; j++) {
      f16x4 v = xw[i * 4 + j];
#pragma unroll
      for (int r = 0; r < 4; r++) acc[i][j][r] = (float)v[r];
    }
  gemm_core(p.A_buf, p.BT_U, smem, t, mBase, nBase, acc);

#pragma unroll
  for (int pp = 0; pp < 2; pp++) {
    __syncthreads();
    if (wc == pp) {
#pragma unroll
      for (int i = 0; i < 4; i++)
#pragma unroll
        for (int j = 0; j < 4; j++) {
          int cl = 16 * j + row16;
#pragma unroll
          for (int r = 0; r < 4; r++) {
            int rr = wr * 64 + 16 * i + 4 * kgrp + r;
            int ch = (cl >> 2) ^ (rr & 7);
            tileF[rr * 64 + ch * 4 + (cl & 3)] = acc[i][j][r];
          }
        }
    }
    __syncthreads();
    int el = t & 15;
    int nb2 = nBase + 64 * pp;
    int eb = nb2 >> 2;
#pragma unroll
    for (int rep = 0; rep < 8; rep++) {
      int ml = rep * 16 + (t >> 4);
      int gm = mBase + ml;
      f32x4 vals = *(const f32x4*)(tileF + ml * 64 + ((el ^ (ml & 7))) * 4);
      float nm = p.nmF[gm];
      size_t ci = (size_t)gm * DD + eb + el;
      float cold = (float)p.c_cur[ci];
      float ig = fsigmoid(vals[0]);
      float og = fsigmoid(vals[1]);
      float fg = fsigmoid(vals[2]);
      float gg = ftanh(vals[3]);
      float cn = (fg * cold + ig * gg) * nm;
      float hn = og * ftanh(cn) * nm;
      p.c_cur[ci] = (f16)cn;
      p.h_cur[ci] = (f16)hn;
      if (last) {
        if (isf32) ((float*)p.outp)[ci] = hn;
        else       ((bf16*)p.outp)[ci] = __float2bfloat16(hn);
      }
    }
  }
}

// ==================== launch ====================
extern "C" void kernel_launch(void* const* d_in, const int* in_sizes, int n_in,
                              void* d_out, int out_size, void* d_ws, size_t ws_size,
                              hipStream_t stream) {
  char* ws = (char*)d_ws;
  f16*   h_cur = (f16*)(ws + 256);                      // 4 MB
  f16*   c_cur = h_cur + (size_t)MM * DD;               // 4 MB
  f16*   A_buf = c_cur + (size_t)MM * DD;               // 8 MB  [h_in|h_out], stride 512
  f16*   X_buf = A_buf + (size_t)MM * 512;              // 8 MB  [x_in|x_out], stride 512
  f16*   BT_W  = X_buf + (size_t)MM * 512;              // 1 MB  rows 4e+g, cols [W_in|W_out]
  f16*   BT_U  = BT_W + (size_t)1024 * 512;             // 1 MB  rows 4e+g, cols [U_in|U_out]
  f16*   XW    = BT_U + (size_t)1024 * 512;             // 16 MB f16 raw acc fragments
  float* biasI = (float*)(XW + (size_t)MM * 1024);      // 4 KB
  float* nmF   = biasI + 1024;
  float* inmF  = nmF + MM;
  float* outmF = inmF + (size_t)MM * KK;

  Params p;
  p.h0 = d_in[0]; p.c0 = d_in[1]; p.x_in = d_in[2]; p.x_out = d_in[3];
  p.W_in = d_in[4]; p.U_in = d_in[5]; p.W_out = d_in[6]; p.U_out = d_in[7];
  p.bvec = d_in[8]; p.in_mask = d_in[9]; p.out_mask = d_in[10]; p.node_mask = d_in[11];
  p.in_nodes = (const int*)d_in[12]; p.out_nodes = (const int*)d_in[13];
  p.biasI = biasI; p.nmF = nmF; p.inmF = inmF; p.outmF = outmF;
  p.h_cur = h_cur; p.c_cur = c_cur; p.A_buf = A_buf; p.X_buf = X_buf;
  p.BT_W = BT_W; p.BT_U = BT_U; p.XW = XW;
  p.outp = d_out;
  // d_in[14] = num_layers (3 from setup; hardcoded for graph capture)

  prep_k<<<PREP_BLOCKS, 256, 0, stream>>>(p);
  gemmx_k<<<dim3(MM / 128, 8), 256, 0, stream>>>(p);   // once: layer-invariant x-part
  for (int l = 0; l < NLAYER; l++) {
    gather_k<<<MM / 4, 256, 0, stream>>>(p);
    gemm_k<<<dim3(MM / 128, 8), 256, 0, stream>>>(p, l == NLAYER - 1);
  }
}

// Round 6
// 199.437 us; speedup vs baseline: 2.9992x; 1.0685x over previous
//
#include <hip/hip_runtime.h>
#include <hip/hip_bf16.h>
#include <cstdint>
#include <cstddef>

typedef __hip_bfloat16 bf16;
typedef _Float16 f16;
typedef __attribute__((ext_vector_type(4))) float f32x4;
typedef __attribute__((ext_vector_type(8))) _Float16 f16x8;
typedef __attribute__((ext_vector_type(4))) _Float16 f16x4;
typedef __attribute__((ext_vector_type(4))) unsigned short u16x4;

#define BB 8
#define NN 1024
#define KK 16
#define DD 256
#define MM (BB * NN)   // 8192 rows
#define NLAYER 3

__device__ __forceinline__ float ldf(const void* p, size_t i, int isf32) {
  return isf32 ? ((const float*)p)[i] : __bfloat162float(((const bf16*)p)[i]);
}

__device__ __forceinline__ f32x4 ldf4(const void* p, size_t vi, int isf32) {
  f32x4 r;
  if (isf32) {
    r = ((const f32x4*)p)[vi];
  } else {
    u16x4 u = ((const u16x4*)p)[vi];
#pragma unroll
    for (int q = 0; q < 4; q++) {
      union { unsigned u; float f; } c;
      c.u = ((unsigned)u[q]) << 16;
      r[q] = c.f;
    }
  }
  return r;
}

__device__ __forceinline__ void gload_lds16(const void* g, void* l) {
  __builtin_amdgcn_global_load_lds(
      (const __attribute__((address_space(1))) unsigned int*)g,
      (__attribute__((address_space(3))) unsigned int*)l, 16, 0, 0);
}

// per-WAVE dtype detect: lane i samples W_in u16[2i]; ballot-vote. No barriers.
__device__ __forceinline__ int detect_isf32_wave(const void* W) {
  int lane = threadIdx.x & 63;
  unsigned short b = ((const unsigned short*)W)[2 * lane];
  int e = (b >> 7) & 0xFF;
  int sane = ((e >= 105 && e <= 130) || (b & 0x7FFF) == 0) ? 1 : 0;
  unsigned long long m = __ballot(sane);
  return (__popcll(m) > 32) ? 0 : 1;
}

// fast transcendentals: v_exp_f32 + v_rcp_f32; clamp keeps them NaN-free.
__device__ __forceinline__ float fsigmoid(float x) {
  float a = fminf(fmaxf(-1.44269504f * x, -126.f), 126.f);
  float e = __builtin_amdgcn_exp2f(a);
  return __builtin_amdgcn_rcpf(1.f + e);
}
__device__ __forceinline__ float ftanh(float x) {
  float a = fminf(fmaxf(2.88539008f * x, -126.f), 126.f);
  float e = __builtin_amdgcn_exp2f(a);
  return 1.f - 2.f * __builtin_amdgcn_rcpf(1.f + e);
}

struct Params {
  const void *h0, *c0, *x_in, *x_out, *W_in, *U_in, *W_out, *U_out, *bvec;
  const void *in_mask, *out_mask, *node_mask;
  const int *in_nodes, *out_nodes;
  float *biasI, *nmF, *inmF, *outmF;
  f16 *h_cur, *c_cur, *A_buf, *X_buf, *BT_W, *BT_U, *XW;
  void* outp;
};

// ---------------- merged prep + weight transpose ----------------
// blocks 0..255: transpose one 64x64 tile of one weight matrix into BT_W/BT_U
//   rows n = 4e+g, cols: BT_W=[W_in|W_out], BT_U=[U_in|U_out], stride 512
// blocks 256+: vectorized converts / packing (4 elems per thread)
#define PREP_VEC_TOTAL (256 + 2048 + 32768 + 32768 + 524288 + 524288)
#define PREP_BLOCKS (256 + (PREP_VEC_TOTAL + 255) / 256)
__global__ void prep_k(Params p) {
  __shared__ float tile[64][65];
  int isf32 = detect_isf32_wave(p.W_in);
  int b = blockIdx.x;
  int t = threadIdx.x;

  if (b < 256) {   // ---- transpose path ----
    int bx = b & 3, by = (b >> 2) & 3, z = b >> 4;
    int g = z & 3, which = z >> 2;
    const void* src = (which == 0) ? p.W_in : (which == 1) ? p.W_out
                     : (which == 2) ? p.U_in : p.U_out;
    f16* dst = (which < 2) ? p.BT_W : p.BT_U;
    int colofs = (which & 1) * 256;
    size_t gbase = (size_t)g * DD * DD;
    int tx = t & 63, ty = t >> 6;
    int d0 = bx * 64, e0 = by * 64;
#pragma unroll
    for (int r = 0; r < 64; r += 4)
      tile[ty + r][tx] = ldf(src, gbase + (size_t)(d0 + ty + r) * DD + e0 + tx, isf32);
    __syncthreads();
#pragma unroll
    for (int r = 0; r < 64; r += 4)
      dst[(size_t)(4 * (e0 + ty + r) + g) * 512 + colofs + d0 + tx] = (f16)tile[tx][ty + r];
    return;
  }

  // ---- vectorized prep path: one vec4 per thread ----
  size_t i = (size_t)(b - 256) * 256 + t;
  const size_t V0 = 256;           // bias vec4s
  const size_t V1 = V0 + 2048;     // node_mask
  const size_t V2 = V1 + 32768;    // in_mask
  const size_t V3 = V2 + 32768;    // out_mask
  const size_t V4 = V3 + 524288;   // h0 + c0
  const size_t V5 = V4 + 524288;   // x pack
  if (i < V0) {
    f32x4 r;
#pragma unroll
    for (int g = 0; g < 4; g++) r[g] = ldf(p.bvec, (size_t)g * 256 + i, isf32);
    ((f32x4*)p.biasI)[i] = r;
  } else if (i < V1) {
    ((f32x4*)p.nmF)[i - V0] = ldf4(p.node_mask, i - V0, isf32);
  } else if (i < V2) {
    ((f32x4*)p.inmF)[i - V1] = ldf4(p.in_mask, i - V1, isf32);
  } else if (i < V3) {
    ((f32x4*)p.outmF)[i - V2] = ldf4(p.out_mask, i - V2, isf32);
  } else if (i < V4) {
    size_t j = i - V3;
    f32x4 hv = ldf4(p.h0, j, isf32);
    f32x4 cv = ldf4(p.c0, j, isf32);
    f16x4 ho, co;
#pragma unroll
    for (int q = 0; q < 4; q++) { ho[q] = (f16)hv[q]; co[q] = (f16)cv[q]; }
    ((f16x4*)p.h_cur)[j] = ho;
    ((f16x4*)p.c_cur)[j] = co;
  } else if (i < V5) {
    size_t j = i - V4;
    size_t m = j >> 6, d4 = (j & 63) * 4;
    f32x4 xi = ldf4(p.x_in, j, isf32);
    f32x4 xo = ldf4(p.x_out, j, isf32);
    f16x4 a, bq;
#pragma unroll
    for (int q = 0; q < 4; q++) { a[q] = (f16)xi[q]; bq[q] = (f16)xo[q]; }
    *(f16x4*)(p.X_buf + m * 512 + d4)       = a;
    *(f16x4*)(p.X_buf + m * 512 + 256 + d4) = bq;
  }
}

// ---------------- gather: one wave per node, shfl broadcast, f16x8 loads ----------------
// XCD-LOCAL mapping: XCD = blockIdx%8 (round-robin dispatch) handles ONLY batch
// (blockIdx&7). Its h-slice (1024 rows x 512 B = 512 KB) is L2-resident across the
// 16x random reuse, instead of all XCDs thrashing the full 8 MB h_cur through L3.
__global__ void gather_k(Params p) {
  int wave = threadIdx.x >> 6;
  int lane = threadIdx.x & 63;
  int m = (blockIdx.x & 7) * 1024 + (blockIdx.x >> 3) * 4 + wave;
  int l5 = lane & 31, dir = lane >> 5;
  int myidx = 0; float mymask = 0.f;
  if (lane < 16)      { myidx = p.in_nodes[(size_t)m * KK + lane];
                        mymask = p.inmF[(size_t)m * KK + lane]; }
  else if (lane < 32) { myidx = p.out_nodes[(size_t)m * KK + lane - 16];
                        mymask = p.outmF[(size_t)m * KK + lane - 16]; }
  const f16* hb = p.h_cur + (size_t)(m >> 10) * NN * DD;
  float acc[8] = {};
#pragma unroll
  for (int k = 0; k < KK; k++) {
    int src = dir * 16 + k;
    int idxk = __shfl(myidx, src);
    float wk = __shfl(mymask, src);
    f16x8 v = *(const f16x8*)(hb + (size_t)idxk * DD + l5 * 8);
#pragma unroll
    for (int q = 0; q < 8; q++) acc[q] += wk * (float)v[q];
  }
  float nm = p.nmF[m];
  f16x8 o;
#pragma unroll
  for (int q = 0; q < 8; q++) o[q] = (f16)(acc[q] * nm);
  *(f16x8*)(p.A_buf + (size_t)m * 512 + dir * 256 + l5 * 8) = o;
}

// XCD-local m-tile remap for the GEMMs: linear dispatch id = x + 64*y -> XCD = x&7.
// Choose m-tile mt = (x&7)*8 + (x>>3) so the tile's batch (mt>>3) == x&7 == XCD.
__device__ __forceinline__ int mtile_of(int bx) { return (bx & 7) * 8 + (bx >> 3); }

// ---------------- unified per-layer GEMM, FIRST layer fuses the old gemmx ----------------
// BM=128 BN=128 BK=64, 4 waves as 2x2, acc[4][4], double-buffered LDS (2x32 KB).
// FIRST=1 (layer 0): 16 K-steps -- steps 0-7 stage (X_buf, BT_W) computing X@W;
//   after step 7 add bias and snapshot acc to XW (f16 raw fragments, same key the
//   later layers read); steps 8-15 stage (A_buf, BT_U) and continue accumulating.
//   Saves: one 512-block dispatch, the layer-0 XW read (16 MB), one acc roundtrip.
// FIRST=0 (layers 1,2): 8 K-steps over (A_buf, BT_U), acc preloaded from XW.
template <int FIRST>
__global__ __launch_bounds__(256, 2)
void gemm_k(Params p, int last) {
  __shared__ __attribute__((aligned(16))) char smem[65536];
  float* tileF = (float*)smem;           // [128][64] f32 epilogue tile (32 KB)
  int isf32 = detect_isf32_wave(p.W_in);
  int t = threadIdx.x;
  int w = t >> 6, lane = t & 63;
  int wr = w >> 1, wc = w & 1;
  int row16 = lane & 15, kgrp = lane >> 4;
  int mBase = mtile_of(blockIdx.x) * 128, nBase = blockIdx.y * 128;

  // ds_read fragment offsets (chunk-swizzled)
  int aoff[2][4], boff[2][4];
#pragma unroll
  for (int sub = 0; sub < 2; sub++) {
    int ch = ((sub * 4 + kgrp) ^ (row16 & 7)) * 8;
#pragma unroll
    for (int i = 0; i < 4; i++) aoff[sub][i] = (wr * 64 + 16 * i + row16) * 64 + ch;
#pragma unroll
    for (int j = 0; j < 4; j++) boff[sub][j] = (wc * 64 + 16 * j + row16) * 64 + ch;
  }
  // pre-swizzled global staging offsets
  int srow = t >> 3;                       // 0..31
  int scol = ((t & 7) ^ (srow & 7)) * 8;
  const f16* gaH0 = p.A_buf + (size_t)(mBase + srow) * 512 + scol;
  const f16* gbU0 = p.BT_U + (size_t)(nBase + srow) * 512 + scol;
  const f16* gaX0 = p.X_buf + (size_t)(mBase + srow) * 512 + scol;
  const f16* gbW0 = p.BT_W + (size_t)(nBase + srow) * 512 + scol;

  const size_t xwkey = ((size_t)(blockIdx.y * 64 + blockIdx.x) * 256 + t) * 16;

  f32x4 acc[4][4];
  if (FIRST) {
#pragma unroll
    for (int i = 0; i < 4; i++)
#pragma unroll
      for (int j = 0; j < 4; j++) acc[i][j] = (f32x4){0.f, 0.f, 0.f, 0.f};
  } else {
    const f16x4* xw = (const f16x4*)p.XW + xwkey;
#pragma unroll
    for (int i = 0; i < 4; i++)
#pragma unroll
      for (int j = 0; j < 4; j++) {
        f16x4 v = xw[i * 4 + j];
#pragma unroll
        for (int r = 0; r < 4; r++) acc[i][j][r] = (float)v[r];
      }
  }

  const int NSTEP = FIRST ? 16 : 8;
  auto stage = [&](int it, int buf) {
    const f16* ga; const f16* gb; int kt;
    if (FIRST && it < 8) { ga = gaX0; gb = gbW0; kt = it * 64; }
    else                 { ga = gaH0; gb = gbU0; kt = (FIRST ? it - 8 : it) * 64; }
    f16* As = (f16*)(smem + buf * 32768);
    f16* Bs = (f16*)(smem + buf * 32768 + 16384);
#pragma unroll
    for (int q = 0; q < 4; q++)
      gload_lds16(ga + kt + (size_t)(32 * q) * 512, As + q * 2048 + t * 8);
#pragma unroll
    for (int q = 0; q < 4; q++)
      gload_lds16(gb + kt + (size_t)(32 * q) * 512, Bs + q * 2048 + t * 8);
  };

  stage(0, 0);
  __syncthreads();   // vmcnt(0) drain

#pragma unroll
  for (int it = 0; it < NSTEP; ++it) {
    int cur = it & 1;
    if (it < NSTEP - 1) stage(it + 1, cur ^ 1);   // issue next tile before compute
    f16* As = (f16*)(smem + cur * 32768);
    f16* Bs = (f16*)(smem + cur * 32768 + 16384);
#pragma unroll
    for (int sub = 0; sub < 2; sub++) {
      f16x8 af[4], bfr[4];
#pragma unroll
      for (int i = 0; i < 4; i++) af[i] = *(const f16x8*)(As + aoff[sub][i]);
#pragma unroll
      for (int j = 0; j < 4; j++) bfr[j] = *(const f16x8*)(Bs + boff[sub][j]);
#pragma unroll
      for (int i = 0; i < 4; i++)
#pragma unroll
        for (int j = 0; j < 4; j++)
          acc[i][j] = __builtin_amdgcn_mfma_f32_16x16x32_f16(af[i], bfr[j], acc[i][j], 0, 0, 0);
    }
    if (FIRST && it == 7) {
      // x-part complete: fold bias in, snapshot to XW for layers 1..L-1.
      // Stores overlap the already-issued step-8 staging loads.
      float bb4[4];
#pragma unroll
      for (int j = 0; j < 4; j++) bb4[j] = p.biasI[nBase + wc * 64 + 16 * j + row16];
      f16x4* dst = (f16x4*)p.XW + xwkey;
#pragma unroll
      for (int i = 0; i < 4; i++)
#pragma unroll
        for (int j = 0; j < 4; j++) {
          f16x4 v;
#pragma unroll
          for (int r = 0; r < 4; r++) {
            acc[i][j][r] += bb4[j];
            v[r] = (f16)acc[i][j][r];
          }
          dst[i * 4 + j] = v;
        }
    }
    __syncthreads();
  }

  // ---------------- fused LSTM epilogue ----------------
#pragma unroll
  for (int pp = 0; pp < 2; pp++) {
    __syncthreads();
    if (wc == pp) {
#pragma unroll
      for (int i = 0; i < 4; i++)
#pragma unroll
        for (int j = 0; j < 4; j++) {
          int cl = 16 * j + row16;
#pragma unroll
          for (int r = 0; r < 4; r++) {
            int rr = wr * 64 + 16 * i + 4 * kgrp + r;
            int ch = (cl >> 2) ^ (rr & 7);
            tileF[rr * 64 + ch * 4 + (cl & 3)] = acc[i][j][r];
          }
        }
    }
    __syncthreads();
    int el = t & 15;
    int nb2 = nBase + 64 * pp;
    int eb = nb2 >> 2;
#pragma unroll
    for (int rep = 0; rep < 8; rep++) {
      int ml = rep * 16 + (t >> 4);
      int gm = mBase + ml;
      f32x4 vals = *(const f32x4*)(tileF + ml * 64 + ((el ^ (ml & 7))) * 4);
      float nm = p.nmF[gm];
      size_t ci = (size_t)gm * DD + eb + el;
      float cold = (float)p.c_cur[ci];
      float ig = fsigmoid(vals[0]);
      float og = fsigmoid(vals[1]);
      float fg = fsigmoid(vals[2]);
      float gg = ftanh(vals[3]);
      float cn = (fg * cold + ig * gg) * nm;
      float hn = og * ftanh(cn) * nm;
      p.c_cur[ci] = (f16)cn;
      p.h_cur[ci] = (f16)hn;
      if (last) {
        if (isf32) ((float*)p.outp)[ci] = hn;
        else       ((bf16*)p.outp)[ci] = __float2bfloat16(hn);
      }
    }
  }
}

// ==================== launch ====================
extern "C" void kernel_launch(void* const* d_in, const int* in_sizes, int n_in,
                              void* d_out, int out_size, void* d_ws, size_t ws_size,
                              hipStream_t stream) {
  char* ws = (char*)d_ws;
  f16*   h_cur = (f16*)(ws + 256);                      // 4 MB
  f16*   c_cur = h_cur + (size_t)MM * DD;               // 4 MB
  f16*   A_buf = c_cur + (size_t)MM * DD;               // 8 MB  [h_in|h_out], stride 512
  f16*   X_buf = A_buf + (size_t)MM * 512;              // 8 MB  [x_in|x_out], stride 512
  f16*   BT_W  = X_buf + (size_t)MM * 512;              // 1 MB  rows 4e+g, cols [W_in|W_out]
  f16*   BT_U  = BT_W + (size_t)1024 * 512;             // 1 MB  rows 4e+g, cols [U_in|U_out]
  f16*   XW    = BT_U + (size_t)1024 * 512;             // 16 MB f16 raw acc fragments
  float* biasI = (float*)(XW + (size_t)MM * 1024);      // 4 KB
  float* nmF   = biasI + 1024;
  float* inmF  = nmF + MM;
  float* outmF = inmF + (size_t)MM * KK;

  Params p;
  p.h0 = d_in[0]; p.c0 = d_in[1]; p.x_in = d_in[2]; p.x_out = d_in[3];
  p.W_in = d_in[4]; p.U_in = d_in[5]; p.W_out = d_in[6]; p.U_out = d_in[7];
  p.bvec = d_in[8]; p.in_mask = d_in[9]; p.out_mask = d_in[10]; p.node_mask = d_in[11];
  p.in_nodes = (const int*)d_in[12]; p.out_nodes = (const int*)d_in[13];
  p.biasI = biasI; p.nmF = nmF; p.inmF = inmF; p.outmF = outmF;
  p.h_cur = h_cur; p.c_cur = c_cur; p.A_buf = A_buf; p.X_buf = X_buf;
  p.BT_W = BT_W; p.BT_U = BT_U; p.XW = XW;
  p.outp = d_out;
  // d_in[14] = num_layers (3 from setup; hardcoded for graph capture)

  prep_k<<<PREP_BLOCKS, 256, 0, stream>>>(p);
  for (int l = 0; l < NLAYER; l++) {
    gather_k<<<MM / 4, 256, 0, stream>>>(p);
    if (l == 0) gemm_k<1><<<dim3(MM / 128, 8), 256, 0, stream>>>(p, l == NLAYER - 1);
    else        gemm_k<0><<<dim3(MM / 128, 8), 256, 0, stream>>>(p, l == NLAYER - 1);
  }
}